// Round 6
// baseline (252.277 us; speedup 1.0000x reference)
//
#include <hip/hip_runtime.h>

// ---------------------------------------------------------------------------
// CausalSelfAttention on MI355X (gfx950), bf16 MFMA pipeline. Round 14.
// B=4, T=2048, C=1024, H=16, D=64.
// Round-14 changes (consolidation after r13's 4-phase regression, which
// matched m196's "coarse phase-split hurts" warning):
//   * gemm_ph256 reverted to the VERIFIED r12 2-phase schedule (66.5us,
//     775 TF): triple-buffer, stage kt+2 split 3+3 across the two phases,
//     counted vmcnt(6), setprio around 16-MFMA clusters.
//   * cvt + weight-transpose merged into ONE `prep` kernel (5 -> 4
//     dispatches; r13 showed ~6-14us saved per eliminated launch).
//   * attn unchanged (pmask fused, dbuf K64, verified r13).
// ---------------------------------------------------------------------------

typedef short bf16x8 __attribute__((ext_vector_type(8)));
typedef float floatx4 __attribute__((ext_vector_type(4)));

#define MFMA16(a, b, c) __builtin_amdgcn_mfma_f32_16x16x32_bf16(a, b, c, 0, 0, 0)

#define ASYNC_COPY16(gp, lp)                                                   \
  __builtin_amdgcn_global_load_lds(                                            \
      (__attribute__((address_space(1))) void*)(gp),                           \
      (__attribute__((address_space(3))) void*)(lp), 16, 0, 0)

#define DRAIN_VMCNT() asm volatile("s_waitcnt vmcnt(0)" ::: "memory")
#define WAIT_VMCNT6() asm volatile("s_waitcnt vmcnt(6)" ::: "memory")

#if defined(__has_builtin)
#if __has_builtin(__builtin_amdgcn_exp2f)
#define EXP2(x) __builtin_amdgcn_exp2f(x)
#endif
#endif
#ifndef EXP2
#define EXP2(x) exp2f(x)
#endif

__device__ __forceinline__ short f2bf(float f) {
  union { float f; unsigned u; } c;
  c.f = f;
  unsigned r = c.u + 0x7fffu + ((c.u >> 16) & 1u);  // RNE
  return (short)(r >> 16);
}

// ---------------- fused prep: x cvt (blocks 0..8191) + W transposes --------
// blocks 8192..9215: tiled transpose+cvt of W_kqv (48 n-tiles) and W_proj
// (16 n-tiles), 16 k-tiles each: tb = bx-8192, n-tile = tb&63, k-tile = tb>>6.
__global__ __launch_bounds__(256) void prep(const float* __restrict__ x,
                                            short* __restrict__ xb,
                                            const float* __restrict__ Wkqv,
                                            short* __restrict__ Wkqvt,
                                            const float* __restrict__ Wproj,
                                            short* __restrict__ Wprojt) {
  __shared__ float buf[64][65];
  const int t = threadIdx.x;
  const int bx = blockIdx.x;
  if (bx < 8192) {
    int i = (bx * 256 + t) * 4;
    float4 v = *(const float4*)&x[i];
    short4 o;
    o.x = f2bf(v.x); o.y = f2bf(v.y); o.z = f2bf(v.z); o.w = f2bf(v.w);
    *(short4*)&xb[i] = o;
    return;
  }
  const int tb = bx - 8192;
  const int nb = tb & 63, kb = tb >> 6;
  const float* in;
  short* out;
  int N, n0;
  if (nb < 48) { in = Wkqv; out = Wkqvt; N = 3072; n0 = nb * 64; }
  else         { in = Wproj; out = Wprojt; N = 1024; n0 = (nb - 48) * 64; }
  const int k0 = kb * 64;
#pragma unroll
  for (int i = 0; i < 4; ++i) {
    int s = t + i * 256;
    int row = s >> 4, c4 = (s & 15) * 4;
    float4 v = *(const float4*)&in[(size_t)(k0 + row) * N + n0 + c4];
    buf[row][c4] = v.x; buf[row][c4 + 1] = v.y;
    buf[row][c4 + 2] = v.z; buf[row][c4 + 3] = v.w;
  }
  __syncthreads();
#pragma unroll
  for (int i = 0; i < 2; ++i) {
    int u = t + i * 256;
    int rn = u >> 3, ch = (u & 7) * 8;
    short tmp[8];
#pragma unroll
    for (int j = 0; j < 8; ++j) tmp[j] = f2bf(buf[ch + j][rn]);
    *(uint4*)&out[(size_t)(n0 + rn) * 1024 + k0 + ch] = *(uint4*)tmp;
  }
}

// -------------------- pipelined GEMM: C = A * Bt^T + bias ------------------
// (exact r12 schedule — verified 66.5us/775TF)
// BM=128 BN=256 BK=64. 512 threads = 8 waves (2M x 4N), 64x64 per wave.
// LDS: 3 buffers x (A 16KB + B 32KB) = 144 KB -> 1 block/CU.
// Schedule per K-step kt (2 phases):
//   ph0: issue A0,A1,B0 of tile kt+2 -> buf[nxt]; ds_read A-frags + B-half0
//        from buf[cur]; setprio1; 16 MFMA; setprio0; s_barrier
//   ph1: issue B1,B2,B3; ds_read B-half1; 16 MFMA;
//        vmcnt(6) (tile kt+1 landed; kt+2 stays in flight); s_barrier
// MODE 0: fp32 dense out. MODE 2: qkv-split epilogue via swizzled LDS re-tile.
template <int MODE>
__global__ __launch_bounds__(512, 2) void gemm_ph256(const short* __restrict__ A,
                                                     const short* __restrict__ Bt,
                                                     const float* __restrict__ bias,
                                                     void* __restrict__ Cout,
                                                     int M, int N, int K) {
  __shared__ short smem[73728];  // 144 KB: A[3][8192] | B[3][16384] @ +24576
  const int tid = threadIdx.x;
  const int lane = tid & 63;
  const int wv = tid >> 6;
  const int l15 = lane & 15, quad = lane >> 4;
  const int xr = l15 & 7;
  const int m0 = blockIdx.y * 128, n0 = blockIdx.x * 256;
  const int wm = (wv >> 2) * 64, wn = (wv & 3) * 64;
  const int NT = K >> 6;  // 16 for K=1024

  floatx4 acc[4][4] = {};

#define STAGE_A(kt, bs, j)                                                     \
  { int c_ = (j) * 512 + tid;                                                  \
    int r_ = c_ >> 3, ch_ = (c_ & 7) ^ (r_ & 7);                               \
    ASYNC_COPY16(&A[(size_t)(m0 + r_) * K + (kt) * 64 + ch_ * 8],              \
                 &smem[(bs) * 8192 + c_ * 8]); }
#define STAGE_B(kt, bs, j)                                                     \
  { int c_ = (j) * 512 + tid;                                                  \
    int r_ = c_ >> 3, ch_ = (c_ & 7) ^ (r_ & 7);                               \
    ASYNC_COPY16(&Bt[(size_t)(n0 + r_) * K + (kt) * 64 + ch_ * 8],             \
                 &smem[24576 + (bs) * 16384 + c_ * 8]); }

  // prologue: tiles 0 and 1 in flight; wait only tile 0 (vmcnt 6)
  STAGE_A(0, 0, 0); STAGE_A(0, 0, 1);
  STAGE_B(0, 0, 0); STAGE_B(0, 0, 1); STAGE_B(0, 0, 2); STAGE_B(0, 0, 3);
  STAGE_A(1, 1, 0); STAGE_A(1, 1, 1);
  STAGE_B(1, 1, 0); STAGE_B(1, 1, 1); STAGE_B(1, 1, 2); STAGE_B(1, 1, 3);
  WAIT_VMCNT6();
  __builtin_amdgcn_s_barrier();

  int cur = 0, nxt = 2;
  for (int kt = 0; kt < NT; ++kt) {
    const bool st = (kt + 2 < NT);
    const short* Asr = &smem[cur * 8192];
    const short* Bsr = &smem[24576 + cur * 16384];

    // ---- phase 0: prefetch A + B0; compute n-half 0 ----
    if (st) { STAGE_A(kt + 2, nxt, 0); STAGE_A(kt + 2, nxt, 1); STAGE_B(kt + 2, nxt, 0); }
    bf16x8 af[4][2], bf0[2][2];
#pragma unroll
    for (int mi = 0; mi < 4; ++mi)
#pragma unroll
      for (int s = 0; s < 2; ++s)
        af[mi][s] = *(const bf16x8*)
            &Asr[(wm + mi * 16 + l15) * 64 + (((s * 4 + quad) ^ xr) * 8)];
#pragma unroll
    for (int nj = 0; nj < 2; ++nj)
#pragma unroll
      for (int s = 0; s < 2; ++s)
        bf0[nj][s] = *(const bf16x8*)
            &Bsr[(wn + nj * 16 + l15) * 64 + (((s * 4 + quad) ^ xr) * 8)];
    __builtin_amdgcn_s_setprio(1);
#pragma unroll
    for (int s = 0; s < 2; ++s)
#pragma unroll
      for (int mi = 0; mi < 4; ++mi)
#pragma unroll
        for (int nj = 0; nj < 2; ++nj)
          acc[mi][nj] = MFMA16(af[mi][s], bf0[nj][s], acc[mi][nj]);
    __builtin_amdgcn_s_setprio(0);
    __builtin_amdgcn_s_barrier();

    // ---- phase 1: prefetch B1-3; compute n-half 1 (A-frags reused) ----
    if (st) { STAGE_B(kt + 2, nxt, 1); STAGE_B(kt + 2, nxt, 2); STAGE_B(kt + 2, nxt, 3); }
    bf16x8 bf1[2][2];
#pragma unroll
    for (int nj = 0; nj < 2; ++nj)
#pragma unroll
      for (int s = 0; s < 2; ++s)
        bf1[nj][s] = *(const bf16x8*)
            &Bsr[(wn + (2 + nj) * 16 + l15) * 64 + (((s * 4 + quad) ^ xr) * 8)];
    __builtin_amdgcn_s_setprio(1);
#pragma unroll
    for (int s = 0; s < 2; ++s)
#pragma unroll
      for (int mi = 0; mi < 4; ++mi)
#pragma unroll
        for (int nj = 0; nj < 2; ++nj)
          acc[mi][2 + nj] = MFMA16(af[mi][s], bf1[nj][s], acc[mi][2 + nj]);
    __builtin_amdgcn_s_setprio(0);
    if (st) { WAIT_VMCNT6(); } else { DRAIN_VMCNT(); }
    __builtin_amdgcn_s_barrier();
    cur = (cur == 2) ? 0 : cur + 1;
    nxt = (nxt == 2) ? 0 : nxt + 1;
  }
#undef STAGE_A
#undef STAGE_B

  if (MODE == 0) {
    float* outf = (float*)Cout;
#pragma unroll
    for (int ni = 0; ni < 4; ++ni) {
      int col = n0 + wn + ni * 16 + l15;
      float bv = bias[col];
#pragma unroll
      for (int mi = 0; mi < 4; ++mi) {
#pragma unroll
        for (int rr = 0; rr < 4; ++rr) {
          int row = m0 + wm + mi * 16 + quad * 4 + rr;
          outf[(size_t)row * N + col] = acc[mi][ni][rr] + bv;
        }
      }
    }
  } else {
    short* outs = (short*)Cout;  // base = Kd; Qd at +QOFF; Vd at +2*QOFF
    const size_t QOFF = (size_t)64 * 2048 * 64;
    const int sec = n0 >> 10;  // 0=K, 1=Q, 2=V (uniform: 256-col tile)
    short* Es = smem;          // epilogue re-tile, 32768 shorts (64 KB)
    if (sec < 2) {
#pragma unroll
      for (int ni = 0; ni < 4; ++ni) {
        int c = wn + ni * 16 + l15;
        float bv = bias[n0 + c];
#pragma unroll
        for (int mi = 0; mi < 4; ++mi) {
          int r0 = wm + mi * 16 + quad * 4;
#pragma unroll
          for (int rr = 0; rr < 4; ++rr) {
            int r = r0 + rr;
            Es[r * 256 + (c ^ (((r >> 2) & 3) << 4))] = f2bf(acc[mi][ni][rr] + bv);
          }
        }
      }
    } else {
#pragma unroll
      for (int ni = 0; ni < 4; ++ni) {
        int c = wn + ni * 16 + l15;
        float bv = bias[n0 + c];
#pragma unroll
        for (int mi = 0; mi < 4; ++mi) {
          int r0 = wm + mi * 16 + quad * 4;
#pragma unroll
          for (int rr = 0; rr < 4; ++rr) {
            int r = r0 + rr;
            Es[c * 128 + (r ^ ((c & 7) << 3))] = f2bf(acc[mi][ni][rr] + bv);
          }
        }
      }
    }
    __syncthreads();
    if (sec < 2) {
#pragma unroll
      for (int jj = 0; jj < 8; ++jj) {
        int idx = jj * 512 + tid;          // 0..4095
        int rr2 = idx >> 5;                // row 0..127
        int cc2 = (idx & 31) * 8;          // col chunk 0..248
        uint4 v = *(const uint4*)&Es[rr2 * 256 + (cc2 ^ (((rr2 >> 2) & 3) << 4))];
        int colg = n0 + cc2;
        int hh = (colg >> 6) & 15, dd = colg & 63;
        int row = m0 + rr2, bb = row >> 11, tt = row & 2047;
        *(uint4*)(outs + (size_t)sec * QOFF +
                  (((size_t)(bb * 16 + hh) * 2048 + tt) * 64 + dd)) = v;
      }
    } else {
#pragma unroll
      for (int jj = 0; jj < 8; ++jj) {
        int idx = jj * 512 + tid;          // 0..4095
        int cd = idx >> 4;                 // out col (d) 0..255
        int rb = (idx & 15) * 8;           // 8-row (t) chunk
        uint4 v = *(const uint4*)&Es[cd * 128 + (rb ^ ((cd & 7) << 3))];
        int colg = n0 + cd;
        int hh = (colg >> 6) & 15, dd = colg & 63;
        int trow = m0 + rb, bb = trow >> 11, tt = trow & 2047;
        *(uint4*)(outs + 2 * QOFF +
                  ((size_t)(bb * 16 + hh) * 64 + dd) * 2048 + tt) = v;
      }
    }
  }
}

// ------------------------------ flash attention ----------------------------
// Q-tile 128, K-tile 64 dbuf, Ks[2]+Vs[2]+Ps = 48 KB -> 3 blocks/CU.
// Padding mask fused: reads pmask (int) directly, bias via cndmask.
__global__ __launch_bounds__(256, 3) void attn_flash8(const short* __restrict__ Qd,
                                                      const short* __restrict__ Kd,
                                                      const short* __restrict__ Vd,
                                                      const int* __restrict__ pmask,
                                                      short* __restrict__ y) {
  constexpr int T = 2048, C = 1024;
  __shared__ short Ks[2][64 * 64];
  __shared__ short Vs[2][64 * 64];
  __shared__ short Ps[4][32][64];

  const int tid = threadIdx.x;
  const int lane = tid & 63, w = tid >> 6;
  const int l15 = lane & 15, quad = lane >> 4;
  const int xr = l15 & 7;
  const int lin = blockIdx.x;
  const int qb = 15 - (lin >> 6);
  const int bh = lin & 63;
  const int b = bh >> 4, h = bh & 15;
  const short* Qb = Qd + (size_t)bh * T * 64;
  const short* Kb = Kd + (size_t)bh * T * 64;
  const short* Vb = Vd + (size_t)bh * 64 * T;
  const int* pmi = &pmask[b * T];
  const int q0 = qb * 128;
  const int nt = (q0 >> 6) + 2;

  const float SCALE2 = 0.18033688011112042f;  // 0.125 * log2(e)

#define STAGE_KV(t, buf)                                                       \
  {                                                                            \
    const short* ksrc_ = Kb + (size_t)((t) * 64) * 64;                         \
    const short* vsrc_ = Vb + (t) * 64;                                        \
    _Pragma("unroll")                                                          \
    for (int j_ = 0; j_ < 2; ++j_) {                                           \
      int c_ = j_ * 256 + tid;                                                 \
      int r_ = c_ >> 3, cc_ = (c_ & 7) ^ (r_ & 7);                             \
      ASYNC_COPY16(ksrc_ + r_ * 64 + cc_ * 8, &Ks[buf][c_ * 8]);               \
      ASYNC_COPY16(vsrc_ + (size_t)r_ * T + cc_ * 8, &Vs[buf][c_ * 8]);        \
    }                                                                          \
  }

  bf16x8 qf[2][2];
#pragma unroll
  for (int mi = 0; mi < 2; ++mi) {
    const short* qp = Qb + (size_t)(q0 + w * 32 + mi * 16 + l15) * 64;
    qf[mi][0] = *(const bf16x8*)&qp[quad * 8];
    qf[mi][1] = *(const bf16x8*)&qp[32 + quad * 8];
  }

  floatx4 Oacc[2][4] = {};
  float lpart[2] = {};

  STAGE_KV(0, 0);
  DRAIN_VMCNT();
  __syncthreads();

  int cur = 0;
#pragma unroll 1
  for (int t = 0; t < nt; ++t) {
    const int k0 = t * 64;
    if (t + 1 < nt) STAGE_KV(t + 1, cur ^ 1);

    floatx4 Sacc[2][4] = {};
#pragma unroll
    for (int s = 0; s < 2; ++s) {
#pragma unroll
      for (int n4 = 0; n4 < 4; ++n4) {
        bf16x8 bK = *(const bf16x8*)
            &Ks[cur][(n4 * 16 + l15) * 64 + (((s * 4 + quad) ^ xr) * 8)];
        Sacc[0][n4] = MFMA16(bK, qf[0][s], Sacc[0][n4]);
        Sacc[1][n4] = MFMA16(bK, qf[1][s], Sacc[1][n4]);
      }
    }

    if (k0 < q0) {
#pragma unroll
      for (int n4 = 0; n4 < 4; ++n4) {
        int4 pm4 = *(const int4*)&pmi[k0 + n4 * 16 + quad * 4];
        float pb[4];
        pb[0] = pm4.x ? 0.0f : -3.0e38f;
        pb[1] = pm4.y ? 0.0f : -3.0e38f;
        pb[2] = pm4.z ? 0.0f : -3.0e38f;
        pb[3] = pm4.w ? 0.0f : -3.0e38f;
#pragma unroll
        for (int mi = 0; mi < 2; ++mi) {
          float p[4];
#pragma unroll
          for (int rr = 0; rr < 4; ++rr) {
            p[rr] = EXP2(fmaf(Sacc[mi][n4][rr], SCALE2, pb[rr]));
            lpart[mi] += p[rr];
          }
          unsigned lo, hi;
          asm("v_cvt_pk_bf16_f32 %0, %1, %2" : "=v"(lo) : "v"(p[0]), "v"(p[1]));
          asm("v_cvt_pk_bf16_f32 %0, %1, %2" : "=v"(hi) : "v"(p[2]), "v"(p[3]));
          uint2 pk; pk.x = lo; pk.y = hi;
          *(uint2*)&Ps[w][mi * 16 + l15]
                      [((n4 * 2 + (quad >> 1)) ^ xr) * 8 + (quad & 1) * 4] = pk;
        }
      }
    } else {
#pragma unroll
      for (int n4 = 0; n4 < 4; ++n4) {
        int4 pm4 = *(const int4*)&pmi[k0 + n4 * 16 + quad * 4];
        float pb[4];
        pb[0] = pm4.x ? 0.0f : -3.0e38f;
        pb[1] = pm4.y ? 0.0f : -3.0e38f;
        pb[2] = pm4.z ? 0.0f : -3.0e38f;
        pb[3] = pm4.w ? 0.0f : -3.0e38f;
        const int colb = n4 * 16 + quad * 4;
#pragma unroll
        for (int mi = 0; mi < 2; ++mi) {
          const int rowb = (q0 - k0) + w * 32 + mi * 16 + l15;
          float p[4];
#pragma unroll
          for (int rr = 0; rr < 4; ++rr) {
            float v = EXP2(fmaf(Sacc[mi][n4][rr], SCALE2, pb[rr]));
            if (colb + rr > rowb) v = 0.f;
            p[rr] = v;
            lpart[mi] += v;
          }
          unsigned lo, hi;
          asm("v_cvt_pk_bf16_f32 %0, %1, %2" : "=v"(lo) : "v"(p[0]), "v"(p[1]));
          asm("v_cvt_pk_bf16_f32 %0, %1, %2" : "=v"(hi) : "v"(p[2]), "v"(p[3]));
          uint2 pk; pk.x = lo; pk.y = hi;
          *(uint2*)&Ps[w][mi * 16 + l15]
                      [((n4 * 2 + (quad >> 1)) ^ xr) * 8 + (quad & 1) * 4] = pk;
        }
      }
    }

#pragma unroll
    for (int ks2 = 0; ks2 < 2; ++ks2) {
      const int pco = (((ks2 * 4 + quad) ^ xr) * 8);
      bf16x8 ap0 = *(const bf16x8*)&Ps[w][l15][pco];
      bf16x8 ap1 = *(const bf16x8*)&Ps[w][16 + l15][pco];
#pragma unroll
      for (int nd = 0; nd < 4; ++nd) {
        bf16x8 bV = *(const bf16x8*)
            &Vs[cur][(nd * 16 + l15) * 64 + (((ks2 * 4 + quad) ^ xr) * 8)];
        Oacc[0][nd] = MFMA16(ap0, bV, Oacc[0][nd]);
        Oacc[1][nd] = MFMA16(ap1, bV, Oacc[1][nd]);
      }
    }

    DRAIN_VMCNT();
    __syncthreads();
    cur ^= 1;
  }
#undef STAGE_KV

#pragma unroll
  for (int mi = 0; mi < 2; ++mi) {
    float s = lpart[mi];
    s += __shfl_xor(s, 16, 64);
    s += __shfl_xor(s, 32, 64);
    float inv_l[4];
#pragma unroll
    for (int rr = 0; rr < 4; ++rr)
      inv_l[rr] = 1.0f / __shfl(s, quad * 4 + rr, 16);
#pragma unroll
    for (int n = 0; n < 4; ++n) {
      int dcol = n * 16 + l15;
#pragma unroll
      for (int rr = 0; rr < 4; ++rr) {
        int rowq = q0 + w * 32 + mi * 16 + quad * 4 + rr;
        y[((size_t)(b * T + rowq)) * C + h * 64 + dcol] =
            f2bf(Oacc[mi][n][rr] * inv_l[rr]);
      }
    }
  }
}

// ---------------------------------------------------------------------------
extern "C" void kernel_launch(void* const* d_in, const int* in_sizes, int n_in,
                              void* d_out, int out_size, void* d_ws, size_t ws_size,
                              hipStream_t stream) {
  constexpr int B = 4, T = 2048, C = 1024;
  constexpr int M = B * T;   // 8192
  constexpr int N1 = 3 * C;  // 3072

  const float* x      = (const float*)d_in[0];
  const float* W_kqv  = (const float*)d_in[1];
  const float* b_kqv  = (const float*)d_in[2];
  const float* W_proj = (const float*)d_in[3];
  const float* b_proj = (const float*)d_in[4];
  const int*   pmask  = (const int*)d_in[5];
  float* out = (float*)d_out;

  const size_t QOFF = (size_t)64 * T * 64;

  short* xb     = (short*)d_ws;                 // [8192,1024] (reused for y)
  short* Wkqvt  = xb + (size_t)M * C;           // [3072,1024]
  short* Wprojt = Wkqvt + (size_t)N1 * C;       // [1024,1024]
  short* qkv    = Wprojt + (size_t)C * C;       // Kd | Qd | Vd
  short* yb     = xb;

  short* Kd = qkv;
  short* Qd = qkv + QOFF;
  short* Vd = qkv + 2 * QOFF;

  prep<<<dim3(8192 + 1024), 256, 0, stream>>>(x, xb, W_kqv, Wkqvt, W_proj, Wprojt);

  gemm_ph256<2><<<dim3(N1 / 256, M / 128), 512, 0, stream>>>(xb, Wkqvt, b_kqv, Kd, M, N1, C);

  attn_flash8<<<dim3(1024), 256, 0, stream>>>(Qd, Kd, Vd, pmask, yb);

  gemm_ph256<0><<<dim3(C / 256, M / 128), 512, 0, stream>>>(yb, Wprojt, b_proj, out, M, C, C);
}